// Round 1
// baseline (374.838 us; speedup 1.0000x reference)
//
#include <hip/hip_runtime.h>
#include <hip/hip_bf16.h>

typedef __bf16 bf16x8 __attribute__((ext_vector_type(8)));
typedef float  f32x4  __attribute__((ext_vector_type(4)));

#define H_  20
#define S_  2048
#define D_  1280
#define HD_ 64
#define M_  4096

__device__ __forceinline__ unsigned short f2bf(float f) {
    union { float f; unsigned int u; } v; v.f = f;
    return (unsigned short)((v.u + 0x7FFFu + ((v.u >> 16) & 1u)) >> 16);
}

__device__ __forceinline__ void gll16(const void* g, void* l) {
    __builtin_amdgcn_global_load_lds(
        (const __attribute__((address_space(1))) unsigned int*)g,
        (__attribute__((address_space(3))) unsigned int*)l, 16, 0, 0);
}

// ---------------- cast f32 -> bf16 (flat) ----------------
__global__ __launch_bounds__(256) void cast_bf16_kernel(
    const float* __restrict__ in, unsigned short* __restrict__ out, int n)
{
    int i = (blockIdx.x * 256 + threadIdx.x) * 4;
    if (i + 3 < n) {
        const float4 v = *(const float4*)(in + i);
        ushort4 o;
        o.x = f2bf(v.x); o.y = f2bf(v.y); o.z = f2bf(v.z); o.w = f2bf(v.w);
        *(ushort4*)(out + i) = o;
    }
}

// ---------------- transpose + cast for weights: Wt[n][k] = W[k][n] ----------------
__global__ __launch_bounds__(256) void transpose_cast_kernel(
    const float* __restrict__ W0, const float* __restrict__ W1,
    const float* __restrict__ W2, const float* __restrict__ W3,
    unsigned short* __restrict__ outbase)
{
    __shared__ unsigned short tile[64][65];
    const float* src = (blockIdx.z == 0) ? W0 : (blockIdx.z == 1) ? W1 :
                       (blockIdx.z == 2) ? W2 : W3;
    unsigned short* dst = outbase + (size_t)blockIdx.z * D_ * D_;
    int n0 = blockIdx.x * 64, k0 = blockIdx.y * 64;
    int tx = threadIdx.x & 63, ty = threadIdx.x >> 6;
#pragma unroll
    for (int i = 0; i < 16; ++i) {
        int row = ty * 16 + i;
        tile[row][tx] = f2bf(src[(size_t)(k0 + row) * D_ + n0 + tx]);
    }
    __syncthreads();
#pragma unroll
    for (int i = 0; i < 16; ++i) {
        int row = ty * 16 + i;
        dst[(size_t)(n0 + row) * D_ + k0 + tx] = tile[tx][row];
    }
}

// ---------------- 128x128 bf16 GEMM, C = A @ Bt^T  (Bt is [N][K]) ----------------
// mode 0: Q layout [b][h][s][hd] (scaled by oscale)   mode 1: K layout [b][h][s][hd]
// mode 2: Vt layout [b][h][hd][s]                      mode 3: f32 rowmajor + bias
__global__ __launch_bounds__(256) void gemm_bf16(
    const unsigned short* __restrict__ A, const unsigned short* __restrict__ Bt,
    void* __restrict__ Cout, const float* __restrict__ bias,
    int Kdim, int Ndim, int mode, float oscale)
{
    __shared__ unsigned short As[128 * 32];
    __shared__ unsigned short Bs[128 * 32];
    const int t = threadIdx.x;
    const int wid = t >> 6, lane = t & 63;
    const int m0 = blockIdx.y * 128, n0 = blockIdx.x * 128;
    const int wm = (wid >> 1) * 64, wn = (wid & 1) * 64;

    f32x4 acc[4][4];
#pragma unroll
    for (int i = 0; i < 4; ++i)
#pragma unroll
        for (int j = 0; j < 4; ++j) acc[i][j] = (f32x4){0.f, 0.f, 0.f, 0.f};

    const int r0 = t >> 2;            // staging row within 64-row half
    const int c0 = (t & 3) * 8;       // staging col (elements)
    const unsigned short* Ab = A + (size_t)m0 * Kdim;
    const unsigned short* Bb = Bt + (size_t)n0 * Kdim;

    for (int k0 = 0; k0 < Kdim; k0 += 32) {
        __syncthreads();
        gll16(Ab + (size_t)(r0) * Kdim + k0 + c0,      (unsigned short*)As + wid * 512);
        gll16(Ab + (size_t)(64 + r0) * Kdim + k0 + c0, (unsigned short*)As + 2048 + wid * 512);
        gll16(Bb + (size_t)(r0) * Kdim + k0 + c0,      (unsigned short*)Bs + wid * 512);
        gll16(Bb + (size_t)(64 + r0) * Kdim + k0 + c0, (unsigned short*)Bs + 2048 + wid * 512);
        __syncthreads();

        bf16x8 af[4], bfr[4];
#pragma unroll
        for (int i = 0; i < 4; ++i)
            af[i] = *(const bf16x8*)(As + (wm + i * 16 + (lane & 15)) * 32 + (lane >> 4) * 8);
#pragma unroll
        for (int i = 0; i < 4; ++i)
            bfr[i] = *(const bf16x8*)(Bs + (wn + i * 16 + (lane & 15)) * 32 + (lane >> 4) * 8);
#pragma unroll
        for (int i = 0; i < 4; ++i)
#pragma unroll
            for (int j = 0; j < 4; ++j)
                acc[i][j] = __builtin_amdgcn_mfma_f32_16x16x32_bf16(af[i], bfr[j], acc[i][j], 0, 0, 0);
    }

    // epilogue
#pragma unroll
    for (int i = 0; i < 4; ++i) {
#pragma unroll
        for (int j = 0; j < 4; ++j) {
            const int gmb = m0 + wm + i * 16 + (lane >> 4) * 4;
            const int gn  = n0 + wn + j * 16 + (lane & 15);
#pragma unroll
            for (int r = 0; r < 4; ++r) {
                float val = acc[i][j][r] * oscale;
                const int m = gmb + r;
                if (mode == 3) {
                    ((float*)Cout)[(size_t)m * Ndim + gn] = val + bias[gn];
                } else {
                    const int b = m >> 11, s = m & 2047;
                    const int h = gn >> 6, d = gn & 63;
                    size_t idx;
                    if (mode == 2) idx = ((size_t)(b * H_ + h) * HD_ + d) * S_ + s;
                    else           idx = ((size_t)(b * H_ + h) * S_ + s) * HD_ + d;
                    ((unsigned short*)Cout)[idx] = f2bf(val);
                }
            }
        }
    }
}

// ---------------- flash attention: Q[b][h][s][64] x K[b][h][s][64] -> O[4096][1280] bf16 ----------------
__global__ __launch_bounds__(256) void attn_kernel(
    const unsigned short* __restrict__ Q, const unsigned short* __restrict__ K,
    const unsigned short* __restrict__ V, unsigned short* __restrict__ O)
{
    __shared__ unsigned short Qs[128 * 64];
    __shared__ unsigned short Ks[64 * 64];
    __shared__ unsigned short Vs[64 * 64];   // [d][t]
    __shared__ unsigned short Ps[4 * 2048];  // per-wave [32][64]

    const int t = threadIdx.x, wid = t >> 6, lane = t & 63;
    const int bh = blockIdx.y;
    const int q0 = blockIdx.x * 128;
    const unsigned short* Qh = Q + (size_t)bh * S_ * HD_;
    const unsigned short* Kh = K + (size_t)bh * S_ * HD_;
    const unsigned short* Vh = V + (size_t)bh * HD_ * S_;

    const int sr = t >> 3;          // staging row (32 rows per issue)
    const int sc = (t & 7) * 8;     // staging col

    // stage Q tile 128x64 (16KB, 4 issues)
#pragma unroll
    for (int j = 0; j < 4; ++j)
        gll16(Qh + (size_t)(q0 + j * 32 + sr) * HD_ + sc, (unsigned short*)Qs + j * 2048 + wid * 512);
    __syncthreads();

    bf16x8 qf[2][2];
#pragma unroll
    for (int qr = 0; qr < 2; ++qr)
#pragma unroll
        for (int kc = 0; kc < 2; ++kc)
            qf[qr][kc] = *(const bf16x8*)(Qs + (wid * 32 + qr * 16 + (lane & 15)) * 64 + kc * 32 + (lane >> 4) * 8);

    f32x4 o_[2][4];
    f32x4 m_[2], l_[2];
#pragma unroll
    for (int qr = 0; qr < 2; ++qr) {
        m_[qr] = (f32x4){-3.0e38f, -3.0e38f, -3.0e38f, -3.0e38f};
        l_[qr] = (f32x4){0.f, 0.f, 0.f, 0.f};
#pragma unroll
        for (int dc = 0; dc < 4; ++dc) o_[qr][dc] = (f32x4){0.f, 0.f, 0.f, 0.f};
    }

    for (int t0 = 0; t0 < S_; t0 += 64) {
        __syncthreads();
        gll16(Kh + (size_t)(t0 + sr) * HD_ + sc,      (unsigned short*)Ks + wid * 512);
        gll16(Kh + (size_t)(t0 + 32 + sr) * HD_ + sc, (unsigned short*)Ks + 2048 + wid * 512);
        gll16(Vh + (size_t)(sr) * S_ + t0 + sc,       (unsigned short*)Vs + wid * 512);
        gll16(Vh + (size_t)(32 + sr) * S_ + t0 + sc,  (unsigned short*)Vs + 2048 + wid * 512);
        __syncthreads();

        // S = Q K^T  (scaled: scale folded into Q)
        f32x4 s_[2][4];
#pragma unroll
        for (int qr = 0; qr < 2; ++qr)
#pragma unroll
            for (int tc = 0; tc < 4; ++tc) s_[qr][tc] = (f32x4){0.f, 0.f, 0.f, 0.f};
#pragma unroll
        for (int tc = 0; tc < 4; ++tc) {
            const bf16x8 kf0 = *(const bf16x8*)(Ks + (tc * 16 + (lane & 15)) * 64 + (lane >> 4) * 8);
            const bf16x8 kf1 = *(const bf16x8*)(Ks + (tc * 16 + (lane & 15)) * 64 + 32 + (lane >> 4) * 8);
#pragma unroll
            for (int qr = 0; qr < 2; ++qr) {
                s_[qr][tc] = __builtin_amdgcn_mfma_f32_16x16x32_bf16(qf[qr][0], kf0, s_[qr][tc], 0, 0, 0);
                s_[qr][tc] = __builtin_amdgcn_mfma_f32_16x16x32_bf16(qf[qr][1], kf1, s_[qr][tc], 0, 0, 0);
            }
        }

        // online softmax (base-2 domain)
#pragma unroll
        for (int qr = 0; qr < 2; ++qr) {
            f32x4 rm = s_[qr][0];
#pragma unroll
            for (int tc = 1; tc < 4; ++tc)
#pragma unroll
                for (int c = 0; c < 4; ++c) rm[c] = fmaxf(rm[c], s_[qr][tc][c]);
#pragma unroll
            for (int mk = 1; mk <= 8; mk <<= 1)
#pragma unroll
                for (int c = 0; c < 4; ++c) rm[c] = fmaxf(rm[c], __shfl_xor(rm[c], mk, 64));
            f32x4 mnew, sf;
#pragma unroll
            for (int c = 0; c < 4; ++c) {
                mnew[c] = fmaxf(m_[qr][c], rm[c]);
                sf[c]   = exp2f(m_[qr][c] - mnew[c]);
            }
            f32x4 rs = (f32x4){0.f, 0.f, 0.f, 0.f};
#pragma unroll
            for (int tc = 0; tc < 4; ++tc)
#pragma unroll
                for (int c = 0; c < 4; ++c) {
                    float p = exp2f(s_[qr][tc][c] - mnew[c]);
                    s_[qr][tc][c] = p;
                    rs[c] += p;
                }
#pragma unroll
            for (int mk = 1; mk <= 8; mk <<= 1)
#pragma unroll
                for (int c = 0; c < 4; ++c) rs[c] += __shfl_xor(rs[c], mk, 64);
#pragma unroll
            for (int c = 0; c < 4; ++c) {
                l_[qr][c] = l_[qr][c] * sf[c] + rs[c];
                m_[qr][c] = mnew[c];
            }
#pragma unroll
            for (int dc = 0; dc < 4; ++dc)
#pragma unroll
                for (int c = 0; c < 4; ++c) o_[qr][dc][c] *= sf[c];
            // write P (bf16) to per-wave LDS, layout [q][t]
#pragma unroll
            for (int tc = 0; tc < 4; ++tc)
#pragma unroll
                for (int c = 0; c < 4; ++c)
                    Ps[wid * 2048 + (qr * 16 + (lane >> 4) * 4 + c) * 64 + tc * 16 + (lane & 15)] =
                        f2bf(s_[qr][tc][c]);
        }

        // PV: O += P @ V  (A from Ps, B from Vs[d][t])
#pragma unroll
        for (int th = 0; th < 2; ++th) {
            const bf16x8 pf0 = *(const bf16x8*)(Ps + wid * 2048 + ((lane & 15)) * 64 + th * 32 + (lane >> 4) * 8);
            const bf16x8 pf1 = *(const bf16x8*)(Ps + wid * 2048 + (16 + (lane & 15)) * 64 + th * 32 + (lane >> 4) * 8);
#pragma unroll
            for (int dc = 0; dc < 4; ++dc) {
                const bf16x8 vf = *(const bf16x8*)(Vs + (dc * 16 + (lane & 15)) * 64 + th * 32 + (lane >> 4) * 8);
                o_[0][dc] = __builtin_amdgcn_mfma_f32_16x16x32_bf16(pf0, vf, o_[0][dc], 0, 0, 0);
                o_[1][dc] = __builtin_amdgcn_mfma_f32_16x16x32_bf16(pf1, vf, o_[1][dc], 0, 0, 0);
            }
        }
    }

    // epilogue: normalize and write O as [b][s][h*64+d] bf16
    const int b = bh / H_, h = bh % H_;
#pragma unroll
    for (int qr = 0; qr < 2; ++qr) {
        f32x4 inv;
#pragma unroll
        for (int c = 0; c < 4; ++c) inv[c] = 1.0f / l_[qr][c];
#pragma unroll
        for (int dc = 0; dc < 4; ++dc)
#pragma unroll
            for (int c = 0; c < 4; ++c) {
                const int srow = q0 + wid * 32 + qr * 16 + (lane >> 4) * 4 + c;
                const int d = dc * 16 + (lane & 15);
                O[(size_t)(b * S_ + srow) * D_ + h * HD_ + d] = f2bf(o_[qr][dc][c] * inv[c]);
            }
    }
}

extern "C" void kernel_launch(void* const* d_in, const int* in_sizes, int n_in,
                              void* d_out, int out_size, void* d_ws, size_t ws_size,
                              hipStream_t stream)
{
    const float* hid = (const float*)d_in[0];
    const float* Wq  = (const float*)d_in[1];
    const float* Wk  = (const float*)d_in[2];
    const float* Wv  = (const float*)d_in[3];
    const float* Wo  = (const float*)d_in[4];
    const float* bo  = (const float*)d_in[5];
    float* out = (float*)d_out;

    char* ws = (char*)d_ws;
    unsigned short* Xb  = (unsigned short*)(ws);                    // 4096x1280 bf16
    unsigned short* Wt  = (unsigned short*)(ws + 10485760);         // 4x 1280x1280 bf16 (transposed)
    unsigned short* Qb  = (unsigned short*)(ws + 23592960);         // [b][h][s][64]
    unsigned short* Kb  = (unsigned short*)(ws + 34078720);         // [b][h][s][64]
    unsigned short* Vb  = (unsigned short*)(ws + 44564480);         // [b][h][64][s]
    unsigned short* Ob  = (unsigned short*)(ws + 55050240);         // [4096][1280]

    cast_bf16_kernel<<<5120, 256, 0, stream>>>(hid, Xb, M_ * D_);
    transpose_cast_kernel<<<dim3(20, 20, 4), 256, 0, stream>>>(Wq, Wk, Wv, Wo, Wt);

    const float SCALE_Q = 0.125f * 1.44269504088896340736f;  // sm_scale * log2(e)
    gemm_bf16<<<dim3(10, 32), 256, 0, stream>>>(Xb, Wt + 0 * 1638400, Qb, nullptr, D_, D_, 0, SCALE_Q);
    gemm_bf16<<<dim3(10, 32), 256, 0, stream>>>(Xb, Wt + 1 * 1638400, Kb, nullptr, D_, D_, 1, 1.0f);
    gemm_bf16<<<dim3(10, 32), 256, 0, stream>>>(Xb, Wt + 2 * 1638400, Vb, nullptr, D_, D_, 2, 1.0f);

    attn_kernel<<<dim3(16, 40), 256, 0, stream>>>(Qb, Kb, Vb, Ob);

    gemm_bf16<<<dim3(10, 32), 256, 0, stream>>>(Ob, Wt + 3 * 1638400, out, bo, D_, D_, 3, 1.0f);
}

// Round 2
// 328.752 us; speedup vs baseline: 1.1402x; 1.1402x over previous
//
#include <hip/hip_runtime.h>
#include <hip/hip_bf16.h>

typedef __bf16 bf16x8 __attribute__((ext_vector_type(8)));
typedef float  f32x4  __attribute__((ext_vector_type(4)));

#define H_  20
#define S_  2048
#define D_  1280
#define HD_ 64
#define M_  4096

__device__ __forceinline__ unsigned short f2bf(float f) {
    union { float f; unsigned int u; } v; v.f = f;
    return (unsigned short)((v.u + 0x7FFFu + ((v.u >> 16) & 1u)) >> 16);
}

__device__ __forceinline__ unsigned short b2u(float f) {
    union { __bf16 b; unsigned short u; } v; v.b = (__bf16)f; return v.u;
}

__device__ __forceinline__ void gll16(const void* g, void* l) {
    __builtin_amdgcn_global_load_lds(
        (const __attribute__((address_space(1))) unsigned int*)g,
        (__attribute__((address_space(3))) unsigned int*)l, 16, 0, 0);
}

// swizzled LDS read: logical (row, 16B-granule g) -> physical granule g ^ (row&7)
#define SWZ(base, row, g) \
    (*(const bf16x8*)((base) + (row) * 64 + (((g) ^ ((row) & 7)) * 8)))

// ---------------- cast f32 -> bf16 (flat) ----------------
__global__ __launch_bounds__(256) void cast_bf16_kernel(
    const float* __restrict__ in, unsigned short* __restrict__ out, int n)
{
    int i = (blockIdx.x * 256 + threadIdx.x) * 4;
    if (i + 3 < n) {
        const float4 v = *(const float4*)(in + i);
        ushort4 o;
        o.x = f2bf(v.x); o.y = f2bf(v.y); o.z = f2bf(v.z); o.w = f2bf(v.w);
        *(ushort4*)(out + i) = o;
    }
}

// ---------------- transpose + cast for weights: Wt[n][k] = W[k][n] ----------------
__global__ __launch_bounds__(256) void transpose_cast_kernel(
    const float* __restrict__ W0, const float* __restrict__ W1,
    const float* __restrict__ W2, const float* __restrict__ W3,
    unsigned short* __restrict__ outbase)
{
    __shared__ unsigned short tile[64][65];
    const float* src = (blockIdx.z == 0) ? W0 : (blockIdx.z == 1) ? W1 :
                       (blockIdx.z == 2) ? W2 : W3;
    unsigned short* dst = outbase + (size_t)blockIdx.z * D_ * D_;
    int n0 = blockIdx.x * 64, k0 = blockIdx.y * 64;
    int tx = threadIdx.x & 63, ty = threadIdx.x >> 6;
#pragma unroll
    for (int i = 0; i < 16; ++i) {
        int row = ty * 16 + i;
        tile[row][tx] = f2bf(src[(size_t)(k0 + row) * D_ + n0 + tx]);
    }
    __syncthreads();
#pragma unroll
    for (int i = 0; i < 16; ++i) {
        int row = ty * 16 + i;
        dst[(size_t)(n0 + row) * D_ + k0 + tx] = tile[tx][row];
    }
}

// ---------------- 128x128 bf16 GEMM, C = A @ Bt^T  (Bt is [N][K]) ----------------
// mode 3: f32 rowmajor + bias
// mode 4: fused QKV epilogue — gn/1280 selects {Q scaled, K, Vt} output
__global__ __launch_bounds__(256) void gemm_bf16(
    const unsigned short* __restrict__ A, const unsigned short* __restrict__ Bt,
    void* __restrict__ C0, void* __restrict__ C1, void* __restrict__ C2,
    const float* __restrict__ bias,
    int Kdim, int Ndim, int mode, float oscale)
{
    __shared__ unsigned short As[128 * 32];
    __shared__ unsigned short Bs[128 * 32];
    const int t = threadIdx.x;
    const int wid = t >> 6, lane = t & 63;
    const int m0 = blockIdx.y * 128, n0 = blockIdx.x * 128;
    const int wm = (wid >> 1) * 64, wn = (wid & 1) * 64;

    f32x4 acc[4][4];
#pragma unroll
    for (int i = 0; i < 4; ++i)
#pragma unroll
        for (int j = 0; j < 4; ++j) acc[i][j] = (f32x4){0.f, 0.f, 0.f, 0.f};

    const int r0 = t >> 2;            // staging row within 64-row half
    const int c0 = (t & 3) * 8;       // staging col (elements)
    const unsigned short* Ab = A + (size_t)m0 * Kdim;
    const unsigned short* Bb = Bt + (size_t)n0 * Kdim;

    for (int k0 = 0; k0 < Kdim; k0 += 32) {
        __syncthreads();
        gll16(Ab + (size_t)(r0) * Kdim + k0 + c0,      (unsigned short*)As + wid * 512);
        gll16(Ab + (size_t)(64 + r0) * Kdim + k0 + c0, (unsigned short*)As + 2048 + wid * 512);
        gll16(Bb + (size_t)(r0) * Kdim + k0 + c0,      (unsigned short*)Bs + wid * 512);
        gll16(Bb + (size_t)(64 + r0) * Kdim + k0 + c0, (unsigned short*)Bs + 2048 + wid * 512);
        __syncthreads();

        bf16x8 af[4], bfr[4];
#pragma unroll
        for (int i = 0; i < 4; ++i)
            af[i] = *(const bf16x8*)(As + (wm + i * 16 + (lane & 15)) * 32 + (lane >> 4) * 8);
#pragma unroll
        for (int i = 0; i < 4; ++i)
            bfr[i] = *(const bf16x8*)(Bs + (wn + i * 16 + (lane & 15)) * 32 + (lane >> 4) * 8);
#pragma unroll
        for (int i = 0; i < 4; ++i)
#pragma unroll
            for (int j = 0; j < 4; ++j)
                acc[i][j] = __builtin_amdgcn_mfma_f32_16x16x32_bf16(af[i], bfr[j], acc[i][j], 0, 0, 0);
    }

    // epilogue
#pragma unroll
    for (int i = 0; i < 4; ++i) {
#pragma unroll
        for (int j = 0; j < 4; ++j) {
            const int gmb = m0 + wm + i * 16 + (lane >> 4) * 4;
            const int gn  = n0 + wn + j * 16 + (lane & 15);
#pragma unroll
            for (int r = 0; r < 4; ++r) {
                float val = acc[i][j][r];
                const int m = gmb + r;
                const int b = m >> 11, s = m & 2047;
                if (mode == 3) {
                    ((float*)C0)[(size_t)m * Ndim + gn] = val + bias[gn];
                } else {
                    // fused QKV: which = 0 (Q, scaled), 1 (K), 2 (V transposed)
                    const int which = gn / 1280;
                    const int nn = gn - which * 1280;
                    const int h = nn >> 6, d = nn & 63;
                    if (which == 0) val *= oscale;
                    size_t idx;
                    void* dst;
                    if (which == 2) { idx = ((size_t)(b * H_ + h) * HD_ + d) * S_ + s; dst = C2; }
                    else            { idx = ((size_t)(b * H_ + h) * S_ + s) * HD_ + d; dst = (which == 0) ? C0 : C1; }
                    ((unsigned short*)dst)[idx] = f2bf(val);
                }
            }
        }
    }
}

// ---------------- flash attention ----------------
// LDS layout (elems): KV buf0 @0 (Ks 4096, Vs 4096), KV buf1 @8192 (also Q staging),
//                     Ps @16384 + wid*2048. Total 24576 elems = 48KB.
__global__ __launch_bounds__(256) void attn_kernel(
    const unsigned short* __restrict__ Q, const unsigned short* __restrict__ K,
    const unsigned short* __restrict__ V, unsigned short* __restrict__ O)
{
    __shared__ unsigned short lds[24576];

    const int t = threadIdx.x, wid = t >> 6, lane = t & 63;
    const int ln15 = lane & 15, ln4 = lane >> 4;
    const int bh = blockIdx.y;
    const int q0 = blockIdx.x * 128;
    const unsigned short* Qh = Q + (size_t)bh * S_ * HD_;
    const unsigned short* Kh = K + (size_t)bh * S_ * HD_;
    const unsigned short* Vh = V + (size_t)bh * HD_ * S_;

    const int srow = t >> 3;                       // staging row 0..31 per issue
    const int scol = (((t & 7) ^ (srow & 7)) * 8); // inverse-swizzled source granule

    // ---- prologue: stage Q (swizzled source) into buf1 region ----
#pragma unroll
    for (int j = 0; j < 4; ++j)
        gll16(Qh + (size_t)(q0 + j * 32 + srow) * HD_ + scol,
              lds + 8192 + j * 2048 + wid * 512);
    __syncthreads();

    bf16x8 qf[2][2];
#pragma unroll
    for (int qr = 0; qr < 2; ++qr)
#pragma unroll
        for (int kc = 0; kc < 2; ++kc)
            qf[qr][kc] = SWZ(lds + 8192, wid * 32 + qr * 16 + ln15, kc * 4 + ln4);

    // ---- stage KV tile 0 into buf0 ----
    {
        unsigned short* base = lds;
        gll16(Kh + (size_t)(srow) * HD_ + scol,          base + wid * 512);
        gll16(Kh + (size_t)(32 + srow) * HD_ + scol,     base + 2048 + wid * 512);
        gll16(Vh + (size_t)srow * S_ + scol,             base + 4096 + wid * 512);
        gll16(Vh + (size_t)(32 + srow) * S_ + scol,      base + 4096 + 2048 + wid * 512);
    }
    __syncthreads();  // drains tile0 loads; all waves done reading Q region

    f32x4 o_[2][4];
    f32x4 m_[2], l_[2];
#pragma unroll
    for (int qr = 0; qr < 2; ++qr) {
        m_[qr] = (f32x4){-3.0e38f, -3.0e38f, -3.0e38f, -3.0e38f};
        l_[qr] = (f32x4){0.f, 0.f, 0.f, 0.f};
#pragma unroll
        for (int dc = 0; dc < 4; ++dc) o_[qr][dc] = (f32x4){0.f, 0.f, 0.f, 0.f};
    }

    unsigned short* Psw = lds + 16384 + wid * 2048;

    for (int it = 0; it < S_ / 64; ++it) {
        const unsigned short* cb = lds + (it & 1) * 8192;   // current KV buffer
        // prefetch next KV tile into other buffer (flies under this tile's compute)
        if (it + 1 < S_ / 64) {
            unsigned short* nb = lds + ((it + 1) & 1) * 8192;
            const int t0 = (it + 1) * 64;
            gll16(Kh + (size_t)(t0 + srow) * HD_ + scol,      nb + wid * 512);
            gll16(Kh + (size_t)(t0 + 32 + srow) * HD_ + scol, nb + 2048 + wid * 512);
            gll16(Vh + (size_t)srow * S_ + t0 + scol,         nb + 4096 + wid * 512);
            gll16(Vh + (size_t)(32 + srow) * S_ + t0 + scol,  nb + 4096 + 2048 + wid * 512);
        }

        // ---- S = Q K^T (scale folded into Q, log2 domain) ----
        f32x4 s_[2][4];
#pragma unroll
        for (int qr = 0; qr < 2; ++qr)
#pragma unroll
            for (int tc = 0; tc < 4; ++tc) s_[qr][tc] = (f32x4){0.f, 0.f, 0.f, 0.f};
#pragma unroll
        for (int tc = 0; tc < 4; ++tc) {
            const bf16x8 kf0 = SWZ(cb, tc * 16 + ln15, ln4);
            const bf16x8 kf1 = SWZ(cb, tc * 16 + ln15, 4 + ln4);
#pragma unroll
            for (int qr = 0; qr < 2; ++qr) {
                s_[qr][tc] = __builtin_amdgcn_mfma_f32_16x16x32_bf16(qf[qr][0], kf0, s_[qr][tc], 0, 0, 0);
                s_[qr][tc] = __builtin_amdgcn_mfma_f32_16x16x32_bf16(qf[qr][1], kf1, s_[qr][tc], 0, 0, 0);
            }
        }

        // ---- online softmax with defer-max (T13) ----
#pragma unroll
        for (int qr = 0; qr < 2; ++qr) {
            f32x4 rm = s_[qr][0];
#pragma unroll
            for (int tc = 1; tc < 4; ++tc)
#pragma unroll
                for (int c = 0; c < 4; ++c) rm[c] = fmaxf(rm[c], s_[qr][tc][c]);
#pragma unroll
            for (int mk = 1; mk <= 8; mk <<= 1)
#pragma unroll
                for (int c = 0; c < 4; ++c) rm[c] = fmaxf(rm[c], __shfl_xor(rm[c], mk, 64));

            float growth = rm[0] - m_[qr][0];
#pragma unroll
            for (int c = 1; c < 4; ++c) growth = fmaxf(growth, rm[c] - m_[qr][c]);
            if (__any(growth > 8.0f)) {
                f32x4 mn, sf;
#pragma unroll
                for (int c = 0; c < 4; ++c) {
                    mn[c] = fmaxf(m_[qr][c], rm[c]);
                    sf[c] = exp2f(m_[qr][c] - mn[c]);
                    l_[qr][c] *= sf[c];
                }
#pragma unroll
                for (int dc = 0; dc < 4; ++dc)
#pragma unroll
                    for (int c = 0; c < 4; ++c) o_[qr][dc][c] *= sf[c];
                m_[qr] = mn;
            }

            f32x4 rs = (f32x4){0.f, 0.f, 0.f, 0.f};
#pragma unroll
            for (int tc = 0; tc < 4; ++tc) {
                const int col = tc * 16 + ln15;
                const int gc = col >> 3, e = col & 7;
#pragma unroll
                for (int c = 0; c < 4; ++c) {
                    float p = exp2f(s_[qr][tc][c] - m_[qr][c]);
                    rs[c] += p;
                    const int q = qr * 16 + ln4 * 4 + c;
                    Psw[q * 64 + ((gc ^ (q & 7)) * 8) + e] = b2u(p);
                }
            }
#pragma unroll
            for (int mk = 1; mk <= 8; mk <<= 1)
#pragma unroll
                for (int c = 0; c < 4; ++c) rs[c] += __shfl_xor(rs[c], mk, 64);
#pragma unroll
            for (int c = 0; c < 4; ++c) l_[qr][c] += rs[c];
        }

        // ---- PV: O += P @ V ----
        const unsigned short* Vb_ = cb + 4096;
#pragma unroll
        for (int th = 0; th < 2; ++th) {
            const bf16x8 pf0 = SWZ(Psw, ln15,      th * 4 + ln4);
            const bf16x8 pf1 = SWZ(Psw, 16 + ln15, th * 4 + ln4);
#pragma unroll
            for (int dc = 0; dc < 4; ++dc) {
                const bf16x8 vf = SWZ(Vb_, dc * 16 + ln15, th * 4 + ln4);
                o_[0][dc] = __builtin_amdgcn_mfma_f32_16x16x32_bf16(pf0, vf, o_[0][dc], 0, 0, 0);
                o_[1][dc] = __builtin_amdgcn_mfma_f32_16x16x32_bf16(pf1, vf, o_[1][dc], 0, 0, 0);
            }
        }

        __syncthreads();  // single barrier: publishes prefetched tile, protects WAR
    }

    // ---- epilogue: normalize, write O as [b][s][h*64+d] bf16 ----
    const int b = bh / H_, h = bh % H_;
#pragma unroll
    for (int qr = 0; qr < 2; ++qr) {
        f32x4 inv;
#pragma unroll
        for (int c = 0; c < 4; ++c) inv[c] = 1.0f / l_[qr][c];
#pragma unroll
        for (int dc = 0; dc < 4; ++dc)
#pragma unroll
            for (int c = 0; c < 4; ++c) {
                const int srow_o = q0 + wid * 32 + qr * 16 + ln4 * 4 + c;
                const int d = dc * 16 + ln15;
                O[(size_t)(b * S_ + srow_o) * D_ + h * HD_ + d] = b2u(o_[qr][dc][c] * inv[c]);
            }
    }
}

extern "C" void kernel_launch(void* const* d_in, const int* in_sizes, int n_in,
                              void* d_out, int out_size, void* d_ws, size_t ws_size,
                              hipStream_t stream)
{
    const float* hid = (const float*)d_in[0];
    const float* Wq  = (const float*)d_in[1];
    const float* Wk  = (const float*)d_in[2];
    const float* Wv  = (const float*)d_in[3];
    const float* Wo  = (const float*)d_in[4];
    const float* bo  = (const float*)d_in[5];
    float* out = (float*)d_out;

    char* ws = (char*)d_ws;
    unsigned short* Xb  = (unsigned short*)(ws);                    // 4096x1280 bf16
    unsigned short* Wt  = (unsigned short*)(ws + 10485760);         // 4x 1280x1280 bf16 (transposed)
    unsigned short* Qb  = (unsigned short*)(ws + 23592960);         // [b][h][s][64]
    unsigned short* Kb  = (unsigned short*)(ws + 34078720);         // [b][h][s][64]
    unsigned short* Vb  = (unsigned short*)(ws + 44564480);         // [b][h][64][s]
    unsigned short* Ob  = (unsigned short*)(ws + 55050240);         // [4096][1280]

    cast_bf16_kernel<<<5120, 256, 0, stream>>>(hid, Xb, M_ * D_);
    transpose_cast_kernel<<<dim3(20, 20, 4), 256, 0, stream>>>(Wq, Wk, Wv, Wo, Wt);

    const float SCALE_Q = 0.125f * 1.44269504088896340736f;  // sm_scale * log2(e)

    // fused QKV projection: Bt = [Wq^T; Wk^T; Wv^T] contiguous = [3840][1280]
    gemm_bf16<<<dim3(30, 32), 256, 0, stream>>>(Xb, Wt, Qb, Kb, Vb, nullptr,
                                                D_, 3840, 4, SCALE_Q);

    attn_kernel<<<dim3(16, 40), 256, 0, stream>>>(Qb, Kb, Vb, Ob);

    gemm_bf16<<<dim3(10, 32), 256, 0, stream>>>(Ob, Wt + 3 * 1638400, out, nullptr, nullptr, bo,
                                                D_, D_, 3, 1.0f);
}

// Round 3
// 245.017 us; speedup vs baseline: 1.5298x; 1.3418x over previous
//
#include <hip/hip_runtime.h>
#include <hip/hip_bf16.h>

typedef __bf16 bf16x8 __attribute__((ext_vector_type(8)));
typedef float  f32x4  __attribute__((ext_vector_type(4)));
typedef float  f32x16 __attribute__((ext_vector_type(16)));

#define H_  20
#define S_  2048
#define D_  1280
#define HD_ 64
#define M_  4096

__device__ __forceinline__ unsigned short f2bf(float f) {
    union { float f; unsigned int u; } v; v.f = f;
    return (unsigned short)((v.u + 0x7FFFu + ((v.u >> 16) & 1u)) >> 16);
}

__device__ __forceinline__ unsigned short b2u(float f) {
    union { __bf16 b; unsigned short u; } v; v.b = (__bf16)f; return v.u;
}

__device__ __forceinline__ unsigned pack2(float lo, float hi) {
    return (unsigned)b2u(lo) | ((unsigned)b2u(hi) << 16);
}

__device__ __forceinline__ void gll16(const void* g, void* l) {
    __builtin_amdgcn_global_load_lds(
        (const __attribute__((address_space(1))) unsigned int*)g,
        (__attribute__((address_space(3))) unsigned int*)l, 16, 0, 0);
}

// swizzled LDS read: logical (row, 16B-granule g) -> physical granule g ^ (row&7)
#define SWZ(base, row, g) \
    (*(const bf16x8*)((base) + (row) * 64 + (((g) ^ ((row) & 7)) * 8)))

// ---------------- cast f32 -> bf16 (flat) ----------------
__global__ __launch_bounds__(256) void cast_bf16_kernel(
    const float* __restrict__ in, unsigned short* __restrict__ out, int n)
{
    int i = (blockIdx.x * 256 + threadIdx.x) * 4;
    if (i + 3 < n) {
        const float4 v = *(const float4*)(in + i);
        ushort4 o;
        o.x = f2bf(v.x); o.y = f2bf(v.y); o.z = f2bf(v.z); o.w = f2bf(v.w);
        *(ushort4*)(out + i) = o;
    }
}

// ---------------- transpose + cast for weights: Wt[n][k] = W[k][n] ----------------
__global__ __launch_bounds__(256) void transpose_cast_kernel(
    const float* __restrict__ W0, const float* __restrict__ W1,
    const float* __restrict__ W2, const float* __restrict__ W3,
    unsigned short* __restrict__ outbase)
{
    __shared__ unsigned short tile[64][65];
    const float* src = (blockIdx.z == 0) ? W0 : (blockIdx.z == 1) ? W1 :
                       (blockIdx.z == 2) ? W2 : W3;
    unsigned short* dst = outbase + (size_t)blockIdx.z * D_ * D_;
    int n0 = blockIdx.x * 64, k0 = blockIdx.y * 64;
    int tx = threadIdx.x & 63, ty = threadIdx.x >> 6;
#pragma unroll
    for (int i = 0; i < 16; ++i) {
        int row = ty * 16 + i;
        tile[row][tx] = f2bf(src[(size_t)(k0 + row) * D_ + n0 + tx]);
    }
    __syncthreads();
#pragma unroll
    for (int i = 0; i < 16; ++i) {
        int row = ty * 16 + i;
        dst[(size_t)(n0 + row) * D_ + k0 + tx] = tile[tx][row];
    }
}

// ---------------- 128x128 bf16 GEMM, C = A @ Bt^T  (Bt is [N][K]) ----------------
// mode 3: f32 rowmajor + bias
// mode 4: fused QKV epilogue — gn/1280 selects {Q scaled, K, Vt} output
__global__ __launch_bounds__(256) void gemm_bf16(
    const unsigned short* __restrict__ A, const unsigned short* __restrict__ Bt,
    void* __restrict__ C0, void* __restrict__ C1, void* __restrict__ C2,
    const float* __restrict__ bias,
    int Kdim, int Ndim, int mode, float oscale)
{
    __shared__ unsigned short As[128 * 32];
    __shared__ unsigned short Bs[128 * 32];
    const int t = threadIdx.x;
    const int wid = t >> 6, lane = t & 63;

    // XCD-bijective swizzle (nwg divisible by 8): group consecutive tiles per XCD
    const int lin = blockIdx.x + blockIdx.y * gridDim.x;
    const int nwg = gridDim.x * gridDim.y;
    const int nl  = (lin & 7) * (nwg >> 3) + (lin >> 3);
    const int bx  = nl % gridDim.x, by = nl / gridDim.x;

    const int m0 = by * 128, n0 = bx * 128;
    const int wm = (wid >> 1) * 64, wn = (wid & 1) * 64;

    f32x4 acc[4][4];
#pragma unroll
    for (int i = 0; i < 4; ++i)
#pragma unroll
        for (int j = 0; j < 4; ++j) acc[i][j] = (f32x4){0.f, 0.f, 0.f, 0.f};

    const int r0 = t >> 2;            // staging row within 64-row half
    const int c0 = (t & 3) * 8;       // staging col (elements)
    const unsigned short* Ab = A + (size_t)m0 * Kdim;
    const unsigned short* Bb = Bt + (size_t)n0 * Kdim;

    for (int k0 = 0; k0 < Kdim; k0 += 32) {
        __syncthreads();
        gll16(Ab + (size_t)(r0) * Kdim + k0 + c0,      (unsigned short*)As + wid * 512);
        gll16(Ab + (size_t)(64 + r0) * Kdim + k0 + c0, (unsigned short*)As + 2048 + wid * 512);
        gll16(Bb + (size_t)(r0) * Kdim + k0 + c0,      (unsigned short*)Bs + wid * 512);
        gll16(Bb + (size_t)(64 + r0) * Kdim + k0 + c0, (unsigned short*)Bs + 2048 + wid * 512);
        __syncthreads();

        bf16x8 af[4], bfr[4];
#pragma unroll
        for (int i = 0; i < 4; ++i)
            af[i] = *(const bf16x8*)(As + (wm + i * 16 + (lane & 15)) * 32 + (lane >> 4) * 8);
#pragma unroll
        for (int i = 0; i < 4; ++i)
            bfr[i] = *(const bf16x8*)(Bs + (wn + i * 16 + (lane & 15)) * 32 + (lane >> 4) * 8);
#pragma unroll
        for (int i = 0; i < 4; ++i)
#pragma unroll
            for (int j = 0; j < 4; ++j)
                acc[i][j] = __builtin_amdgcn_mfma_f32_16x16x32_bf16(af[i], bfr[j], acc[i][j], 0, 0, 0);
    }

    // epilogue
#pragma unroll
    for (int i = 0; i < 4; ++i) {
#pragma unroll
        for (int j = 0; j < 4; ++j) {
            const int gmb = m0 + wm + i * 16 + (lane >> 4) * 4;
            const int gn  = n0 + wn + j * 16 + (lane & 15);
#pragma unroll
            for (int r = 0; r < 4; ++r) {
                float val = acc[i][j][r];
                const int m = gmb + r;
                const int b = m >> 11, s = m & 2047;
                if (mode == 3) {
                    ((float*)C0)[(size_t)m * Ndim + gn] = val + bias[gn];
                } else {
                    // fused QKV: which = 0 (Q, scaled), 1 (K), 2 (V transposed)
                    const int which = gn / 1280;
                    const int nn = gn - which * 1280;
                    const int h = nn >> 6, d = nn & 63;
                    if (which == 0) val *= oscale;
                    size_t idx;
                    void* dst;
                    if (which == 2) { idx = ((size_t)(b * H_ + h) * HD_ + d) * S_ + s; dst = C2; }
                    else            { idx = ((size_t)(b * H_ + h) * S_ + s) * HD_ + d; dst = (which == 0) ? C0 : C1; }
                    ((unsigned short*)dst)[idx] = f2bf(val);
                }
            }
        }
    }
}

// ---------------- flash attention, swapped-operand 32x32 structure ----------------
// Per wave: 32 q-rows. Lane l owns q = l&31 end-to-end (S cols, softmax stats, O^T cols).
// LDS: buf0 @0 (K 4096 el, V 4096 el), buf1 @8192 (aliases Q staging). 32KB total.
__global__ __launch_bounds__(256) void attn_kernel(
    const unsigned short* __restrict__ Q, const unsigned short* __restrict__ K,
    const unsigned short* __restrict__ V, unsigned short* __restrict__ O)
{
    __shared__ unsigned short lds[16384];

    const int t = threadIdx.x, wid = t >> 6, lane = t & 63;
    const int ln31 = lane & 31, lhi = lane >> 5;

    // XCD-bijective swizzle: 640 wgs -> 80 per XCD -> 5 heads per XCD (K/V 2.5MB < L2)
    const int lin = blockIdx.x + blockIdx.y * 16;
    const int nl  = (lin & 7) * 80 + (lin >> 3);
    const int qtile = nl & 15, bh = nl >> 4;

    const int q0 = qtile * 128;
    const unsigned short* Qh = Q + (size_t)bh * S_ * HD_;
    const unsigned short* Kh = K + (size_t)bh * S_ * HD_;
    const unsigned short* Vh = V + (size_t)bh * HD_ * S_;

    const int srow = t >> 3;                 // staging row 0..31 per issue
    const int scol = (((t & 7) ^ (srow & 7)) * 8);

    // ---- stage Q (128x64) into buf1 region ----
#pragma unroll
    for (int j = 0; j < 4; ++j)
        gll16(Qh + (size_t)(q0 + j * 32 + srow) * HD_ + scol,
              lds + 8192 + j * 2048 + wid * 512);
    __syncthreads();

    // Q B-operand frags: lane holds Q[q = ln31][d = j*16 + lhi*8 + e]
    bf16x8 qf[4];
    {
        const int row = wid * 32 + ln31;
#pragma unroll
        for (int j = 0; j < 4; ++j)
            qf[j] = SWZ(lds + 8192, row, j * 2 + lhi);
    }

    // ---- stage KV tile 0 into buf0 ----
    gll16(Kh + (size_t)(srow) * HD_ + scol,      lds + wid * 512);
    gll16(Kh + (size_t)(32 + srow) * HD_ + scol, lds + 2048 + wid * 512);
    gll16(Vh + (size_t)srow * S_ + scol,         lds + 4096 + wid * 512);
    gll16(Vh + (size_t)(32 + srow) * S_ + scol,  lds + 4096 + 2048 + wid * 512);
    __syncthreads();   // drains KV0 loads AND this wave's Q ds_reads (pre-alias)

    f32x16 ot[2];
#pragma unroll
    for (int r = 0; r < 16; ++r) { ot[0][r] = 0.f; ot[1][r] = 0.f; }
    float m_ = -3.0e38f, l_ = 0.f;

    for (int it = 0; it < S_ / 64; ++it) {
        const unsigned short* cb = lds + (it & 1) * 8192;
        if (it + 1 < S_ / 64) {
            unsigned short* nb = lds + ((it + 1) & 1) * 8192;
            const int t0 = (it + 1) * 64;
            gll16(Kh + (size_t)(t0 + srow) * HD_ + scol,      nb + wid * 512);
            gll16(Kh + (size_t)(t0 + 32 + srow) * HD_ + scol, nb + 2048 + wid * 512);
            gll16(Vh + (size_t)srow * S_ + t0 + scol,         nb + 4096 + wid * 512);
            gll16(Vh + (size_t)(32 + srow) * S_ + t0 + scol,  nb + 4096 + 2048 + wid * 512);
        }

        // ---- S^T = K Q^T : st[h] holds S[kt = h*32 + pat(reg,lhi)][q = ln31] ----
        f32x16 st[2];
#pragma unroll
        for (int r = 0; r < 16; ++r) { st[0][r] = 0.f; st[1][r] = 0.f; }
        __builtin_amdgcn_s_setprio(1);
#pragma unroll
        for (int h = 0; h < 2; ++h) {
            const int row = h * 32 + ln31;
#pragma unroll
            for (int j = 0; j < 4; ++j) {
                const bf16x8 kf = SWZ(cb, row, j * 2 + lhi);
                st[h] = __builtin_amdgcn_mfma_f32_32x32x16_bf16(kf, qf[j], st[h], 0, 0, 0);
            }
        }
        __builtin_amdgcn_s_setprio(0);

        // ---- lane-local online softmax (log2 domain; scale folded into Q) ----
        float rm = -3.0e38f;
#pragma unroll
        for (int h = 0; h < 2; ++h)
#pragma unroll
            for (int r = 0; r < 16; ++r) rm = fmaxf(rm, st[h][r]);
        rm = fmaxf(rm, __shfl_xor(rm, 32));

        if (__any(rm - m_ > 8.0f)) {
            const float mn = fmaxf(m_, rm);
            const float sf = exp2f(m_ - mn);
            l_ *= sf;
#pragma unroll
            for (int h = 0; h < 2; ++h)
#pragma unroll
                for (int r = 0; r < 16; ++r) ot[h][r] *= sf;
            m_ = mn;
        }

        float rs = 0.f;
#pragma unroll
        for (int h = 0; h < 2; ++h)
#pragma unroll
            for (int r = 0; r < 16; ++r) {
                const float p = exp2f(st[h][r] - m_);
                st[h][r] = p;
                rs += p;
            }
        rs += __shfl_xor(rs, 32);
        l_ += rs;

        // ---- build P frags in-register (T12): pa[c] = P[q=ln31][kt=c*16+lhi*8+e] ----
        bf16x8 pa[4];
#pragma unroll
        for (int c = 0; c < 4; ++c) {
            const int hh = c >> 1, rb = (c & 1) * 8;
            const unsigned wA = pack2(st[hh][rb + 0], st[hh][rb + 1]);
            const unsigned wB = pack2(st[hh][rb + 2], st[hh][rb + 3]);
            const unsigned wC = pack2(st[hh][rb + 4], st[hh][rb + 5]);
            const unsigned wD = pack2(st[hh][rb + 6], st[hh][rb + 7]);
            auto s0 = __builtin_amdgcn_permlane32_swap(wA, wC, false, false);
            auto s1 = __builtin_amdgcn_permlane32_swap(wB, wD, false, false);
            union { unsigned i[4]; bf16x8 v; } u;
            u.i[0] = s0[0]; u.i[1] = s1[0]; u.i[2] = s0[1]; u.i[3] = s1[1];
            pa[c] = u.v;
        }

        // ---- O^T += V^T P : ot[h] holds O[dv = h*32 + pat(reg,lhi)][q = ln31] ----
        __builtin_amdgcn_s_setprio(1);
#pragma unroll
        for (int h = 0; h < 2; ++h) {
            const int row = h * 32 + ln31;
#pragma unroll
            for (int c = 0; c < 4; ++c) {
                const bf16x8 vf = SWZ(cb + 4096, row, c * 2 + lhi);
                ot[h] = __builtin_amdgcn_mfma_f32_32x32x16_bf16(vf, pa[c], ot[h], 0, 0, 0);
            }
        }
        __builtin_amdgcn_s_setprio(0);

        __syncthreads();  // publishes prefetched tile (vmcnt drain), protects WAR
    }

    // ---- epilogue: lane-local normalize; write O[b][s][h*64+dv] bf16 ----
    const int b = bh / H_, hh = bh % H_;
    const int qg = q0 + wid * 32 + ln31;
    const float inv = 1.0f / l_;
    unsigned short* Orow = O + (size_t)(b * S_ + qg) * D_ + hh * HD_;
#pragma unroll
    for (int h = 0; h < 2; ++h)
#pragma unroll
        for (int g = 0; g < 4; ++g) {
            ushort4 w;
            w.x = b2u(ot[h][g * 4 + 0] * inv);
            w.y = b2u(ot[h][g * 4 + 1] * inv);
            w.z = b2u(ot[h][g * 4 + 2] * inv);
            w.w = b2u(ot[h][g * 4 + 3] * inv);
            *(ushort4*)(Orow + h * 32 + lhi * 4 + g * 8) = w;
        }
}

extern "C" void kernel_launch(void* const* d_in, const int* in_sizes, int n_in,
                              void* d_out, int out_size, void* d_ws, size_t ws_size,
                              hipStream_t stream)
{
    const float* hid = (const float*)d_in[0];
    const float* Wq  = (const float*)d_in[1];
    const float* Wk  = (const float*)d_in[2];
    const float* Wv  = (const float*)d_in[3];
    const float* Wo  = (const float*)d_in[4];
    const float* bo  = (const float*)d_in[5];
    float* out = (float*)d_out;

    char* ws = (char*)d_ws;
    unsigned short* Xb  = (unsigned short*)(ws);                    // 4096x1280 bf16
    unsigned short* Wt  = (unsigned short*)(ws + 10485760);         // 4x 1280x1280 bf16 (transposed)
    unsigned short* Qb  = (unsigned short*)(ws + 23592960);         // [b][h][s][64]
    unsigned short* Kb  = (unsigned short*)(ws + 34078720);         // [b][h][s][64]
    unsigned short* Vb  = (unsigned short*)(ws + 44564480);         // [b][h][64][s]
    unsigned short* Ob  = (unsigned short*)(ws + 55050240);         // [4096][1280]

    cast_bf16_kernel<<<5120, 256, 0, stream>>>(hid, Xb, M_ * D_);
    transpose_cast_kernel<<<dim3(20, 20, 4), 256, 0, stream>>>(Wq, Wk, Wv, Wo, Wt);

    const float SCALE_Q = 0.125f * 1.44269504088896340736f;  // sm_scale * log2(e)

    // fused QKV projection: Bt = [Wq^T; Wk^T; Wv^T] contiguous = [3840][1280]
    gemm_bf16<<<dim3(30, 32), 256, 0, stream>>>(Xb, Wt, Qb, Kb, Vb, nullptr,
                                                D_, 3840, 4, SCALE_Q);

    attn_kernel<<<dim3(16, 40), 256, 0, stream>>>(Qb, Kb, Vb, Ob);

    gemm_bf16<<<dim3(10, 32), 256, 0, stream>>>(Ob, Wt + 3 * 1638400, out, nullptr, nullptr, bo,
                                                D_, D_, 3, 1.0f);
}

// Round 4
// 231.773 us; speedup vs baseline: 1.6173x; 1.0571x over previous
//
#include <hip/hip_runtime.h>
#include <hip/hip_bf16.h>

typedef __bf16 bf16x8 __attribute__((ext_vector_type(8)));
typedef float  f32x4  __attribute__((ext_vector_type(4)));
typedef float  f32x16 __attribute__((ext_vector_type(16)));

#define H_  20
#define S_  2048
#define D_  1280
#define HD_ 64
#define M_  4096

__device__ __forceinline__ unsigned short f2bf(float f) {
    union { float f; unsigned int u; } v; v.f = f;
    return (unsigned short)((v.u + 0x7FFFu + ((v.u >> 16) & 1u)) >> 16);
}

__device__ __forceinline__ unsigned short b2u(float f) {
    union { __bf16 b; unsigned short u; } v; v.b = (__bf16)f; return v.u;
}

// packed f32x2 -> bf16x2 (lo in low half), single HW instr
__device__ __forceinline__ unsigned cvtpk(float lo, float hi) {
    unsigned r;
    asm("v_cvt_pk_bf16_f32 %0, %1, %2" : "=v"(r) : "v"(lo), "v"(hi));
    return r;
}

__device__ __forceinline__ void gll16(const void* g, void* l) {
    __builtin_amdgcn_global_load_lds(
        (const __attribute__((address_space(1))) unsigned int*)g,
        (__attribute__((address_space(3))) unsigned int*)l, 16, 0, 0);
}

// attn LDS (128B rows, 8x16B granules): phys granule = g ^ (row&7)
#define SWZ(base, row, g) \
    (*(const bf16x8*)((base) + (row) * 64 + (((g) ^ ((row) & 7)) * 8)))

// gemm LDS (64B rows, 4x16B granules): phys granule = g ^ ((row>>1)&3)
// -> per 16-lane group: 8 distinct bank-starts x2 = 2-way (free)
#define SWZG(base, row, g) \
    (*(const bf16x8*)((base) + (row) * 32 + ((((g) ^ (((row) >> 1) & 3)) * 8))))

// ---------------- cast f32 -> bf16 (flat) ----------------
__global__ __launch_bounds__(256) void cast_bf16_kernel(
    const float* __restrict__ in, unsigned short* __restrict__ out, int n)
{
    int i = (blockIdx.x * 256 + threadIdx.x) * 4;
    if (i + 3 < n) {
        const float4 v = *(const float4*)(in + i);
        ushort4 o;
        o.x = f2bf(v.x); o.y = f2bf(v.y); o.z = f2bf(v.z); o.w = f2bf(v.w);
        *(ushort4*)(out + i) = o;
    }
}

// ---------------- transpose + cast for weights: Wt[n][k] = W[k][n] ----------------
__global__ __launch_bounds__(256) void transpose_cast_kernel(
    const float* __restrict__ W0, const float* __restrict__ W1,
    const float* __restrict__ W2, const float* __restrict__ W3,
    unsigned short* __restrict__ outbase)
{
    __shared__ unsigned short tile[64][65];
    const float* src = (blockIdx.z == 0) ? W0 : (blockIdx.z == 1) ? W1 :
                       (blockIdx.z == 2) ? W2 : W3;
    unsigned short* dst = outbase + (size_t)blockIdx.z * D_ * D_;
    int n0 = blockIdx.x * 64, k0 = blockIdx.y * 64;
    int tx = threadIdx.x & 63, ty = threadIdx.x >> 6;
#pragma unroll
    for (int i = 0; i < 16; ++i) {
        int row = ty * 16 + i;
        tile[row][tx] = f2bf(src[(size_t)(k0 + row) * D_ + n0 + tx]);
    }
    __syncthreads();
#pragma unroll
    for (int i = 0; i < 16; ++i) {
        int row = ty * 16 + i;
        dst[(size_t)(n0 + row) * D_ + k0 + tx] = tile[tx][row];
    }
}

// ---------------- 128x128 bf16 GEMM, C = A @ Bt^T  (Bt is [N][K]) ----------------
// 2-phase prefetch: stage(next) -> compute(cur) -> one barrier per K-step.
// mode 3: f32 rowmajor + bias ; mode 4: fused QKV epilogue
__global__ __launch_bounds__(256) void gemm_bf16(
    const unsigned short* __restrict__ A, const unsigned short* __restrict__ Bt,
    void* __restrict__ C0, void* __restrict__ C1, void* __restrict__ C2,
    const float* __restrict__ bias,
    int Kdim, int Ndim, int mode, float oscale)
{
    __shared__ unsigned short sh[16384];   // A0,A1,B0,B1 each 4096 el (8KB)
    const int t = threadIdx.x;
    const int wid = t >> 6, lane = t & 63;

    // XCD-bijective swizzle (nwg divisible by 8)
    const int lin = blockIdx.x + blockIdx.y * gridDim.x;
    const int nwg = gridDim.x * gridDim.y;
    const int nl  = (lin & 7) * (nwg >> 3) + (lin >> 3);
    const int bx  = nl % gridDim.x, by = nl / gridDim.x;

    const int m0 = by * 128, n0 = bx * 128;
    const int wm = (wid >> 1) * 64, wn = (wid & 1) * 64;
    const int ln15 = lane & 15, ln4 = lane >> 4;

    f32x4 acc[4][4];
#pragma unroll
    for (int i = 0; i < 4; ++i)
#pragma unroll
        for (int j = 0; j < 4; ++j) acc[i][j] = (f32x4){0.f, 0.f, 0.f, 0.f};

    const int r0 = t >> 2;                                   // staging row 0..63
    const int c0s = (((t & 3) ^ ((r0 >> 1) & 3)) * 8);       // inverse-swizzled src granule
    const unsigned short* Ab = A + (size_t)m0 * Kdim;
    const unsigned short* Bb = Bt + (size_t)n0 * Kdim;
    const int nk = Kdim >> 5;

    // prologue: stage k-step 0 into buf 0
    gll16(Ab + (size_t)(r0) * Kdim + c0s,      sh + wid * 512);
    gll16(Ab + (size_t)(64 + r0) * Kdim + c0s, sh + 2048 + wid * 512);
    gll16(Bb + (size_t)(r0) * Kdim + c0s,      sh + 8192 + wid * 512);
    gll16(Bb + (size_t)(64 + r0) * Kdim + c0s, sh + 8192 + 2048 + wid * 512);
    __syncthreads();

    for (int kk = 0; kk < nk; ++kk) {
        const int cur = kk & 1;
        if (kk + 1 < nk) {
            const int k0 = (kk + 1) << 5;
            unsigned short* An = sh + (cur ^ 1) * 4096;
            unsigned short* Bn = sh + 8192 + (cur ^ 1) * 4096;
            gll16(Ab + (size_t)(r0) * Kdim + k0 + c0s,      An + wid * 512);
            gll16(Ab + (size_t)(64 + r0) * Kdim + k0 + c0s, An + 2048 + wid * 512);
            gll16(Bb + (size_t)(r0) * Kdim + k0 + c0s,      Bn + wid * 512);
            gll16(Bb + (size_t)(64 + r0) * Kdim + k0 + c0s, Bn + 2048 + wid * 512);
        }
        const unsigned short* Ac = sh + cur * 4096;
        const unsigned short* Bc = sh + 8192 + cur * 4096;

        bf16x8 af[4], bfr[4];
#pragma unroll
        for (int i = 0; i < 4; ++i) af[i]  = SWZG(Ac, wm + i * 16 + ln15, ln4);
#pragma unroll
        for (int i = 0; i < 4; ++i) bfr[i] = SWZG(Bc, wn + i * 16 + ln15, ln4);
        __builtin_amdgcn_s_setprio(1);
#pragma unroll
        for (int i = 0; i < 4; ++i)
#pragma unroll
            for (int j = 0; j < 4; ++j)
                acc[i][j] = __builtin_amdgcn_mfma_f32_16x16x32_bf16(af[i], bfr[j], acc[i][j], 0, 0, 0);
        __builtin_amdgcn_s_setprio(0);
        __syncthreads();   // drains prefetch (vmcnt) + protects WAR on cur
    }

    // epilogue
#pragma unroll
    for (int i = 0; i < 4; ++i) {
#pragma unroll
        for (int j = 0; j < 4; ++j) {
            const int gmb = m0 + wm + i * 16 + ln4 * 4;
            const int gn  = n0 + wn + j * 16 + ln15;
#pragma unroll
            for (int r = 0; r < 4; ++r) {
                float val = acc[i][j][r];
                const int m = gmb + r;
                const int b = m >> 11, s = m & 2047;
                if (mode == 3) {
                    ((float*)C0)[(size_t)m * Ndim + gn] = val + bias[gn];
                } else {
                    const int which = gn / 1280;
                    const int nn = gn - which * 1280;
                    const int h = nn >> 6, d = nn & 63;
                    if (which == 0) val *= oscale;
                    size_t idx;
                    void* dst;
                    if (which == 2) { idx = ((size_t)(b * H_ + h) * HD_ + d) * S_ + s; dst = C2; }
                    else            { idx = ((size_t)(b * H_ + h) * S_ + s) * HD_ + d; dst = (which == 0) ? C0 : C1; }
                    ((unsigned short*)dst)[idx] = f2bf(val);
                }
            }
        }
    }
}

// ---------------- flash attention, swapped-operand 32x32, 2 waves x 32 q-rows ----------------
__global__ __launch_bounds__(128) void attn_kernel(
    const unsigned short* __restrict__ Q, const unsigned short* __restrict__ K,
    const unsigned short* __restrict__ V, unsigned short* __restrict__ O)
{
    __shared__ unsigned short lds[16384];   // buf0 @0 (K 4096, V 4096), buf1 @8192 (aliases Q)

    const int t = threadIdx.x, wid = t >> 6, lane = t & 63;
    const int ln31 = lane & 31, lhi = lane >> 5;

    // XCD-bijective: 1280 wgs -> 160/XCD -> 5 heads/XCD (K/V 2.5MB < 4MB L2)
    const int lin = blockIdx.x + blockIdx.y * 32;
    const int nl  = (lin & 7) * 160 + (lin >> 3);
    const int qtile = nl & 31, bh = nl >> 5;

    const int q0 = qtile * 64;
    const unsigned short* Qh = Q + (size_t)bh * S_ * HD_;
    const unsigned short* Kh = K + (size_t)bh * S_ * HD_;
    const unsigned short* Vh = V + (size_t)bh * HD_ * S_;

    const int srow = t >> 3;                       // staging row 0..15 per issue
    const int scol = (((t & 7) ^ (srow & 7)) * 8); // inverse-swizzled source granule

    // ---- stage Q (64x64) into buf1 region ----
#pragma unroll
    for (int j = 0; j < 4; ++j)
        gll16(Qh + (size_t)(q0 + j * 16 + srow) * HD_ + scol,
              lds + 8192 + j * 1024 + wid * 512);
    __syncthreads();

    bf16x8 qf[4];
    {
        const int row = wid * 32 + ln31;
#pragma unroll
        for (int j = 0; j < 4; ++j)
            qf[j] = SWZ(lds + 8192, row, j * 2 + lhi);
    }

    // ---- stage KV tile 0 into buf0 ----
#pragma unroll
    for (int j = 0; j < 4; ++j) {
        gll16(Kh + (size_t)(j * 16 + srow) * HD_ + scol, lds + j * 1024 + wid * 512);
        gll16(Vh + (size_t)(j * 16 + srow) * S_ + scol,  lds + 4096 + j * 1024 + wid * 512);
    }
    __syncthreads();   // drains KV0 loads; all waves done with Q region reads

    f32x16 ot[2];
#pragma unroll
    for (int r = 0; r < 16; ++r) { ot[0][r] = 0.f; ot[1][r] = 0.f; }
    float m_ = -3.0e38f, l_ = 0.f;

    for (int it = 0; it < S_ / 64; ++it) {
        const unsigned short* cb = lds + (it & 1) * 8192;
        if (it + 1 < S_ / 64) {
            unsigned short* nb = lds + ((it + 1) & 1) * 8192;
            const int t0 = (it + 1) * 64;
#pragma unroll
            for (int j = 0; j < 4; ++j) {
                gll16(Kh + (size_t)(t0 + j * 16 + srow) * HD_ + scol, nb + j * 1024 + wid * 512);
                gll16(Vh + (size_t)(j * 16 + srow) * S_ + t0 + scol,  nb + 4096 + j * 1024 + wid * 512);
            }
        }

        // ---- S^T = K Q^T ----
        f32x16 st[2];
#pragma unroll
        for (int r = 0; r < 16; ++r) { st[0][r] = 0.f; st[1][r] = 0.f; }
        __builtin_amdgcn_s_setprio(1);
#pragma unroll
        for (int h = 0; h < 2; ++h) {
            const int row = h * 32 + ln31;
#pragma unroll
            for (int j = 0; j < 4; ++j) {
                const bf16x8 kf = SWZ(cb, row, j * 2 + lhi);
                st[h] = __builtin_amdgcn_mfma_f32_32x32x16_bf16(kf, qf[j], st[h], 0, 0, 0);
            }
        }
        __builtin_amdgcn_s_setprio(0);

        // ---- row max: pairwise tree (depth 4) + one cross-half swap ----
        float mx[8];
#pragma unroll
        for (int i = 0; i < 8; ++i)
            mx[i] = fmaxf(fmaxf(st[0][i], st[0][i + 8]), fmaxf(st[1][i], st[1][i + 8]));
#pragma unroll
        for (int i = 0; i < 4; ++i) mx[i] = fmaxf(mx[i], mx[i + 4]);
        float rm = fmaxf(fmaxf(mx[0], mx[1]), fmaxf(mx[2], mx[3]));
        rm = fmaxf(rm, __shfl_xor(rm, 32));

        // ---- defer-max (T13): rescale only on large growth ----
        if (__any(rm - m_ > 8.0f)) {
            const float mn = fmaxf(m_, rm);
            const float sf = exp2f(m_ - mn);
            l_ *= sf;
#pragma unroll
            for (int h = 0; h < 2; ++h)
#pragma unroll
                for (int r = 0; r < 16; ++r) ot[h][r] *= sf;
            m_ = mn;
        }

        // ---- P = exp2(S - m), tree sum ----
        float p[32];
#pragma unroll
        for (int h = 0; h < 2; ++h)
#pragma unroll
            for (int r = 0; r < 16; ++r)
                p[h * 16 + r] = exp2f(st[h][r] - m_);

        float s8[8];
#pragma unroll
        for (int i = 0; i < 8; ++i)
            s8[i] = (p[i] + p[i + 8]) + (p[i + 16] + p[i + 24]);
#pragma unroll
        for (int i = 0; i < 4; ++i) s8[i] += s8[i + 4];
        float rs = (s8[0] + s8[1]) + (s8[2] + s8[3]);
        rs += __shfl_xor(rs, 32);
        l_ += rs;

        // ---- pack P to bf16 frags in-register (T12): 16 cvt_pk + 8 permlane ----
        bf16x8 pa[4];
#pragma unroll
        for (int c = 0; c < 4; ++c) {
            const float* pp = p + c * 8;
            const unsigned wA = cvtpk(pp[0], pp[1]);
            const unsigned wB = cvtpk(pp[2], pp[3]);
            const unsigned wC = cvtpk(pp[4], pp[5]);
            const unsigned wD = cvtpk(pp[6], pp[7]);
            auto s0 = __builtin_amdgcn_permlane32_swap(wA, wC, false, false);
            auto s1 = __builtin_amdgcn_permlane32_swap(wB, wD, false, false);
            union { unsigned i[4]; bf16x8 v; } u;
            u.i[0] = s0[0]; u.i[1] = s1[0]; u.i[2] = s0[1]; u.i[3] = s1[1];
            pa[c] = u.v;
        }

        // ---- O^T += V^T P ----
        __builtin_amdgcn_s_setprio(1);
#pragma unroll
        for (int h = 0; h < 2; ++h) {
            const int row = h * 32 + ln31;
#pragma unroll
            for (int c = 0; c < 4; ++c) {
                const bf16x8 vf = SWZ(cb + 4096, row, c * 2 + lhi);
                ot[h] = __builtin_amdgcn_mfma_f32_32x32x16_bf16(vf, pa[c], ot[h], 0, 0, 0);
            }
        }
        __builtin_amdgcn_s_setprio(0);

        __syncthreads();  // publishes prefetched tile, protects WAR
    }

    // ---- epilogue: normalize, write O[b][s][h*64+dv] bf16 ----
    const int b = bh / H_, hh = bh % H_;
    const int qg = q0 + wid * 32 + ln31;
    const float inv = 1.0f / l_;
    unsigned short* Orow = O + (size_t)(b * S_ + qg) * D_ + hh * HD_;
#pragma unroll
    for (int h = 0; h < 2; ++h)
#pragma unroll
        for (int g = 0; g < 4; ++g) {
            ushort4 w;
            w.x = b2u(ot[h][g * 4 + 0] * inv);
            w.y = b2u(ot[h][g * 4 + 1] * inv);
            w.z = b2u(ot[h][g * 4 + 2] * inv);
            w.w = b2u(ot[h][g * 4 + 3] * inv);
            *(ushort4*)(Orow + h * 32 + lhi * 4 + g * 8) = w;
        }
}

extern "C" void kernel_launch(void* const* d_in, const int* in_sizes, int n_in,
                              void* d_out, int out_size, void* d_ws, size_t ws_size,
                              hipStream_t stream)
{
    const float* hid = (const float*)d_in[0];
    const float* Wq  = (const float*)d_in[1];
    const float* Wk  = (const float*)d_in[2];
    const float* Wv  = (const float*)d_in[3];
    const float* Wo  = (const float*)d_in[4];
    const float* bo  = (const float*)d_in[5];
    float* out = (float*)d_out;

    char* ws = (char*)d_ws;
    unsigned short* Xb  = (unsigned short*)(ws);                    // 4096x1280 bf16
    unsigned short* Wt  = (unsigned short*)(ws + 10485760);         // 4x 1280x1280 bf16 (transposed)
    unsigned short* Qb  = (unsigned short*)(ws + 23592960);         // [b][h][s][64]
    unsigned short* Kb  = (unsigned short*)(ws + 34078720);         // [b][h][s][64]
    unsigned short* Vb  = (unsigned short*)(ws + 44564480);         // [b][h][64][s]
    unsigned short* Ob  = (unsigned short*)(ws + 55050240);         // [4096][1280]

    cast_bf16_kernel<<<5120, 256, 0, stream>>>(hid, Xb, M_ * D_);
    transpose_cast_kernel<<<dim3(20, 20, 4), 256, 0, stream>>>(Wq, Wk, Wv, Wo, Wt);

    const float SCALE_Q = 0.125f * 1.44269504088896340736f;  // sm_scale * log2(e)

    // fused QKV projection: Bt = [Wq^T; Wk^T; Wv^T] contiguous = [3840][1280]
    gemm_bf16<<<dim3(30, 32), 256, 0, stream>>>(Xb, Wt, Qb, Kb, Vb, nullptr,
                                                D_, 3840, 4, SCALE_Q);

    attn_kernel<<<dim3(32, 40), 128, 0, stream>>>(Qb, Kb, Vb, Ob);

    gemm_bf16<<<dim3(10, 32), 256, 0, stream>>>(Ob, Wt + 3 * 1638400, out, nullptr, nullptr, bo,
                                                D_, D_, 3, 1.0f);
}